// Round 6
// baseline (408.063 us; speedup 1.0000x reference)
//
#include <hip/hip_runtime.h>
#include <math.h>

#define NB 64
#define NQ 300
#define NP 6
#define ND 256
#define NF 512
#define NCL 396
#define NT 10

typedef float f4 __attribute__((ext_vector_type(4)));

__device__ __forceinline__ float dot4(f4 a, f4 b) {
    return a.x * b.x + a.y * b.y + a.z * b.z + a.w * b.w;
}
__device__ __forceinline__ float wred(float s) {
    #pragma unroll
    for (int o = 32; o; o >>= 1) s += __shfl_down(s, o, 64);
    return s;
}

// ---------------------------------------------------------------------------
// K1: blocks 0..63 -> per-class masked mean pool + key-padding bias
//     blocks 64+   -> feat global-average-pool rows (nontemporal stream).
// ---------------------------------------------------------------------------
__global__ __launch_bounds__(256) void pool_cls_kernel(
    const float* __restrict__ pred, const float* __restrict__ hs,
    const float* __restrict__ f0, const float* __restrict__ f1,
    const float* __restrict__ f2, const float* __restrict__ f3,
    float* __restrict__ pooled, float* __restrict__ tokG,
    float* __restrict__ biasW)
{
    const int bid = blockIdx.x;
    const int tid = threadIdx.x;
    __shared__ float shm[1824];

    if (bid < NB) {
        const int b = bid;
        float* maskL = shm;
        float* countsL = shm + 1800;
        for (int i = tid; i < NQ * NP; i += 256) {
            float x = pred[(size_t)b * NQ * NP + i];
            float sg = 1.f / (1.f + expf(-x));
            maskL[i] = (sg > 0.3f) ? 1.f : 0.f;
        }
        __syncthreads();
        if (tid < NP) {
            float c = 0.f;
            for (int q = 0; q < NQ; q++) c += maskL[q * NP + tid];
            countsL[tid] = c;
        }
        __syncthreads();
        float acc[NP] = {0.f, 0.f, 0.f, 0.f, 0.f, 0.f};
        const float* hsb = hs + (size_t)b * NQ * ND + tid;
        for (int q = 0; q < NQ; q++) {
            float h = hsb[(size_t)q * ND];
            #pragma unroll
            for (int p = 0; p < NP; p++) acc[p] += maskL[q * NP + p] * h;
        }
        bool anyv = false;
        #pragma unroll
        for (int p = 0; p < NP; p++) anyv = anyv || (countsL[p] > 0.f);
        #pragma unroll
        for (int p = 0; p < NP; p++) {
            float cm = acc[p] / fmaxf(countsL[p], 1.f);
            if (p == 0 && !anyv) cm = hs[(size_t)b * NQ * ND + tid];
            tokG[(size_t)b * 1536 + p * ND + tid] = cm;
        }
        if (tid < 16) {
            float bv = 0.f;
            if (tid < NP) {
                bool v = countsL[tid] > 0.f;
                if (tid == 0 && !anyv) v = true;
                bv = v ? 0.f : -1e30f;
            }
            biasW[b * 16 + tid] = bv;
        }
        return;
    }

    const int row = bid - NB;
    const int scale = row >> 14;
    const int rr = row & 16383;
    const int b = rr >> 8;
    const int d = rr & 255;
    const float* src;
    int n;
    switch (scale) {
        case 0: src = f0; n = 96 * 96; break;
        case 1: src = f1; n = 48 * 48; break;
        case 2: src = f2; n = 24 * 24; break;
        default: src = f3; n = 12 * 12; break;
    }
    const f4* p4 = reinterpret_cast<const f4*>(src + ((size_t)b * ND + d) * (size_t)n);
    int n4 = n >> 2;
    float s = 0.f;
    for (int i = tid; i < n4; i += 256) {
        f4 v = __builtin_nontemporal_load(&p4[i]);
        s += v.x + v.y + v.z + v.w;
    }
    s = wred(s);
    int wid = tid >> 6, lane = tid & 63;
    if (lane == 0) shm[wid] = s;
    __syncthreads();
    if (tid == 0) {
        float t = shm[0] + shm[1] + shm[2] + shm[3];
        pooled[((size_t)b * 4 + scale) * ND + d] = t / (float)n;
    }
}

// ---------------------------------------------------------------------------
// K2: fused per-batch transformer. 64 blocks x 512 threads.
// Column-blocked GEMMs: thread owns T columns; one wave-uniform x read from
// LDS feeds T columns' FMAs (LDS instruction count / T).
// ---------------------------------------------------------------------------
__global__ __launch_bounds__(512) void xform_kernel(
    const float* __restrict__ pooled, const float* __restrict__ tokG,
    const float* __restrict__ biasW,
    const float* __restrict__ ipw, const float* __restrict__ ipb,
    const float* __restrict__ inw, const float* __restrict__ inb,
    const float* __restrict__ ow, const float* __restrict__ ob,
    const float* __restrict__ l1w, const float* __restrict__ l1b,
    const float* __restrict__ l2w, const float* __restrict__ l2b,
    const float* __restrict__ n1w, const float* __restrict__ n1b,
    const float* __restrict__ n2w, const float* __restrict__ n2b,
    const float* __restrict__ c1w, const float* __restrict__ c1b,
    const float* __restrict__ c2w, const float* __restrict__ c2b,
    float* __restrict__ out)
{
    const int b = blockIdx.x;
    const int tid = threadIdx.x;
    const int lane = tid & 63;
    const int wv = tid >> 6;

    __shared__ __align__(16) float xs[NT * ND];     // 2560 current x
    __shared__ __align__(16) float qs[4 * NT * ND]; // 10240 qkv / ff2 partials
    __shared__ __align__(16) float xr[NT * ND];     // 2560 residual / ct
    __shared__ __align__(16) float tmp[NT * NF];    // 5120 pld / h1 / hbuf
    __shared__ float sc[800];
    __shared__ float stats[32];
    __shared__ float biasK[16];

    float* pld = tmp;

    for (int i = tid; i < 1536; i += 512) xs[i] = tokG[(size_t)b * 1536 + i];
    for (int i = tid; i < 1024; i += 512) pld[i] = pooled[(size_t)b * 1024 + i];
    if (tid < 16) biasK[tid] = biasW[b * 16 + tid];
    __syncthreads();

    const f4* xs4 = reinterpret_cast<const f4*>(xs);

    // ---- img tokens: thread owns col c for all 4 scales ----
    if (tid < 256) {
        const int c = tid;
        const f4* w0 = reinterpret_cast<const f4*>(ipw + (size_t)(0 * ND + c) * ND);
        const f4* w1 = reinterpret_cast<const f4*>(ipw + (size_t)(1 * ND + c) * ND);
        const f4* w2 = reinterpret_cast<const f4*>(ipw + (size_t)(2 * ND + c) * ND);
        const f4* w3 = reinterpret_cast<const f4*>(ipw + (size_t)(3 * ND + c) * ND);
        const f4* p4 = reinterpret_cast<const f4*>(pld);
        float a0 = 0.f, a1 = 0.f, a2 = 0.f, a3 = 0.f;
        for (int k4 = 0; k4 < 64; k4++) {
            a0 += dot4(w0[k4], p4[k4]);
            a1 += dot4(w1[k4], p4[64 + k4]);
            a2 += dot4(w2[k4], p4[128 + k4]);
            a3 += dot4(w3[k4], p4[192 + k4]);
        }
        // defer xs writes until all pld (tmp) reads done this phase
        xr[c] = a0 + ipb[c];
        xr[ND + c] = a1 + ipb[ND + c];
        xr[2 * ND + c] = a2 + ipb[2 * ND + c];
        xr[3 * ND + c] = a3 + ipb[3 * ND + c];
    }
    __syncthreads();
    if (tid < 256) {
        #pragma unroll
        for (int i = 0; i < 4; i++) xs[(6 + i) * ND + tid] = xr[i * ND + tid];
    }
    __syncthreads();

    for (int l = 0; l < 2; l++) {
        // ---- (a) QKV: 256 owners x 3 cols, full K. wave-uniform x reads ----
        if (tid < 256) {
            const int c = tid;
            const f4* w0 = reinterpret_cast<const f4*>(inw + ((size_t)l * 768 + c) * ND);
            const f4* w1 = reinterpret_cast<const f4*>(inw + ((size_t)l * 768 + c + 256) * ND);
            const f4* w2 = reinterpret_cast<const f4*>(inw + ((size_t)l * 768 + c + 512) * ND);
            float acc0[NT], acc1[NT], acc2[NT];
            #pragma unroll
            for (int r = 0; r < NT; r++) { acc0[r] = 0.f; acc1[r] = 0.f; acc2[r] = 0.f; }
            for (int k4 = 0; k4 < 64; k4++) {
                f4 a = w0[k4], bb = w1[k4], cc = w2[k4];
                #pragma unroll
                for (int r = 0; r < NT; r++) {
                    f4 xv = xs4[r * 64 + k4];
                    acc0[r] += dot4(a, xv);
                    acc1[r] += dot4(bb, xv);
                    acc2[r] += dot4(cc, xv);
                }
            }
            float b0 = inb[l * 768 + c], b1 = inb[l * 768 + c + 256], b2 = inb[l * 768 + c + 512];
            #pragma unroll
            for (int r = 0; r < NT; r++) {
                qs[r * 768 + c] = acc0[r] + b0;
                qs[r * 768 + c + 256] = acc1[r] + b1;
                qs[r * 768 + c + 512] = acc2[r] + b2;
            }
        }
        __syncthreads();

        // ---- (b) scores + bias ----
        for (int t = tid; t < 800; t += 512) {
            int h = t / 100, rem = t - 100 * h;
            int qr = rem / 10, kr = rem - 10 * qr;
            const float* qp = &qs[qr * 768 + h * 32];
            const float* kp = &qs[kr * 768 + ND + h * 32];
            float s = 0.f;
            #pragma unroll
            for (int dh = 0; dh < 32; dh++) s += qp[dh] * kp[dh];
            sc[t] = s * 0.17677669529663687f + biasK[kr];
        }
        __syncthreads();

        // ---- (c) softmax ----
        if (tid < 80) {
            float* row = &sc[tid * 10];
            float m = row[0];
            #pragma unroll
            for (int k = 1; k < 10; k++) m = fmaxf(m, row[k]);
            float ss = 0.f;
            #pragma unroll
            for (int k = 0; k < 10; k++) { float e = expf(row[k] - m); row[k] = e; ss += e; }
            float inv = 1.f / ss;
            #pragma unroll
            for (int k = 0; k < 10; k++) row[k] *= inv;
        }
        __syncthreads();

        // ---- (d) attn @ V -> xr (attn-out buffer this phase) ----
        for (int idx = tid; idx < NT * ND; idx += 512) {
            int r = idx >> 8, col = idx & 255, h = col >> 5;
            float s = 0.f;
            #pragma unroll
            for (int kr = 0; kr < 10; kr++)
                s += sc[h * 100 + r * 10 + kr] * qs[kr * 768 + 512 + col];
            xr[idx] = s;
        }
        __syncthreads();

        // ---- (e) out_proj: 128 owners x 2 cols, fused residual -> qs rows ----
        if (tid < 128) {
            const int c = tid;
            const f4* w0 = reinterpret_cast<const f4*>(ow + ((size_t)l * ND + c) * ND);
            const f4* w1 = reinterpret_cast<const f4*>(ow + ((size_t)l * ND + c + 128) * ND);
            const f4* ao4 = reinterpret_cast<const f4*>(xr);
            float acc0[NT], acc1[NT];
            #pragma unroll
            for (int r = 0; r < NT; r++) { acc0[r] = 0.f; acc1[r] = 0.f; }
            for (int k4 = 0; k4 < 64; k4++) {
                f4 a = w0[k4], bb = w1[k4];
                #pragma unroll
                for (int r = 0; r < NT; r++) {
                    f4 av = ao4[r * 64 + k4];
                    acc0[r] += dot4(a, av);
                    acc1[r] += dot4(bb, av);
                }
            }
            float b0 = ob[l * ND + c], b1 = ob[l * ND + c + 128];
            #pragma unroll
            for (int r = 0; r < NT; r++) {
                qs[r * ND + c] = xs[r * ND + c] + acc0[r] + b0;
                qs[r * ND + c + 128] = xs[r * ND + c + 128] + acc1[r] + b1;
            }
        }
        __syncthreads();

        // ---- (f) LN1: qs(resid) -> xs ----
        for (int r = wv; r < NT; r += 8) {
            float v0 = qs[r * ND + lane], v1 = qs[r * ND + 64 + lane];
            float v2 = qs[r * ND + 128 + lane], v3 = qs[r * ND + 192 + lane];
            float s = wred(v0 + v1 + v2 + v3);
            float q = wred(v0 * v0 + v1 * v1 + v2 * v2 + v3 * v3);
            if (lane == 0) {
                float m = s * (1.f / ND);
                stats[r] = m;
                stats[16 + r] = rsqrtf(fmaxf(q * (1.f / ND) - m * m, 0.f) + 1e-5f);
            }
        }
        __syncthreads();
        for (int i = tid; i < NT * ND; i += 512) {
            int r = i >> 8, c = i & 255;
            xs[i] = (qs[i] - stats[r]) * stats[16 + r] * n1w[l * ND + c] + n1b[l * ND + c];
        }
        __syncthreads();

        // ---- (g) FF1: 128 owners x 4 cols -> tmp (h1) ----
        if (tid < 128) {
            const int c = tid;
            const f4* w0 = reinterpret_cast<const f4*>(l1w + ((size_t)l * NF + c) * ND);
            const f4* w1 = reinterpret_cast<const f4*>(l1w + ((size_t)l * NF + c + 128) * ND);
            const f4* w2 = reinterpret_cast<const f4*>(l1w + ((size_t)l * NF + c + 256) * ND);
            const f4* w3 = reinterpret_cast<const f4*>(l1w + ((size_t)l * NF + c + 384) * ND);
            float acc0[NT], acc1[NT], acc2[NT], acc3[NT];
            #pragma unroll
            for (int r = 0; r < NT; r++) { acc0[r] = 0.f; acc1[r] = 0.f; acc2[r] = 0.f; acc3[r] = 0.f; }
            for (int k4 = 0; k4 < 64; k4++) {
                f4 a = w0[k4], bb = w1[k4], cc = w2[k4], dd = w3[k4];
                #pragma unroll
                for (int r = 0; r < NT; r++) {
                    f4 xv = xs4[r * 64 + k4];
                    acc0[r] += dot4(a, xv);
                    acc1[r] += dot4(bb, xv);
                    acc2[r] += dot4(cc, xv);
                    acc3[r] += dot4(dd, xv);
                }
            }
            float b0 = l1b[l * NF + c], b1 = l1b[l * NF + c + 128];
            float b2 = l1b[l * NF + c + 256], b3 = l1b[l * NF + c + 384];
            #pragma unroll
            for (int r = 0; r < NT; r++) {
                tmp[r * NF + c] = fmaxf(acc0[r] + b0, 0.f);
                tmp[r * NF + c + 128] = fmaxf(acc1[r] + b1, 0.f);
                tmp[r * NF + c + 256] = fmaxf(acc2[r] + b2, 0.f);
                tmp[r * NF + c + 384] = fmaxf(acc3[r] + b3, 0.f);
            }
        }
        __syncthreads();

        // ---- (h) FF2: 64 owners x 4 cols x 4-way K-split -> partials in qs ----
        if (tid < 256) {
            const int o = tid & 63;
            const int kh = tid >> 6;           // wave-uniform
            const f4* w0 = reinterpret_cast<const f4*>(l2w + ((size_t)l * ND + o) * NF + kh * 128);
            const f4* w1 = reinterpret_cast<const f4*>(l2w + ((size_t)l * ND + o + 64) * NF + kh * 128);
            const f4* w2 = reinterpret_cast<const f4*>(l2w + ((size_t)l * ND + o + 128) * NF + kh * 128);
            const f4* w3 = reinterpret_cast<const f4*>(l2w + ((size_t)l * ND + o + 192) * NF + kh * 128);
            const f4* h14 = reinterpret_cast<const f4*>(tmp);
            float acc0[NT], acc1[NT], acc2[NT], acc3[NT];
            #pragma unroll
            for (int r = 0; r < NT; r++) { acc0[r] = 0.f; acc1[r] = 0.f; acc2[r] = 0.f; acc3[r] = 0.f; }
            for (int k4 = 0; k4 < 32; k4++) {
                f4 a = w0[k4], bb = w1[k4], cc = w2[k4], dd = w3[k4];
                #pragma unroll
                for (int r = 0; r < NT; r++) {
                    f4 hv = h14[r * 128 + kh * 32 + k4];
                    acc0[r] += dot4(a, hv);
                    acc1[r] += dot4(bb, hv);
                    acc2[r] += dot4(cc, hv);
                    acc3[r] += dot4(dd, hv);
                }
            }
            #pragma unroll
            for (int r = 0; r < NT; r++) {
                qs[kh * 2560 + r * ND + o] = acc0[r];
                qs[kh * 2560 + r * ND + o + 64] = acc1[r];
                qs[kh * 2560 + r * ND + o + 128] = acc2[r];
                qs[kh * 2560 + r * ND + o + 192] = acc3[r];
            }
        }
        __syncthreads();
        for (int i = tid; i < NT * ND; i += 512)
            xr[i] = xs[i] + qs[i] + qs[2560 + i] + qs[5120 + i] + qs[7680 + i]
                  + l2b[l * ND + (i & 255)];
        __syncthreads();

        // ---- (i) LN2: xr -> xs ----
        for (int r = wv; r < NT; r += 8) {
            float v0 = xr[r * ND + lane], v1 = xr[r * ND + 64 + lane];
            float v2 = xr[r * ND + 128 + lane], v3 = xr[r * ND + 192 + lane];
            float s = wred(v0 + v1 + v2 + v3);
            float q = wred(v0 * v0 + v1 * v1 + v2 * v2 + v3 * v3);
            if (lane == 0) {
                float m = s * (1.f / ND);
                stats[r] = m;
                stats[16 + r] = rsqrtf(fmaxf(q * (1.f / ND) - m * m, 0.f) + 1e-5f);
            }
        }
        __syncthreads();
        for (int i = tid; i < NT * ND; i += 512) {
            int r = i >> 8, c = i & 255;
            xs[i] = (xr[i] - stats[r]) * stats[16 + r] * n2w[l * ND + c] + n2b[l * ND + c];
        }
        __syncthreads();
    }

    // ---- masked mean pool -> xr[0..256) ----
    if (tid < ND) {
        float len = 0.f, s = 0.f;
        #pragma unroll
        for (int r = 0; r < NT; r++) {
            float v = (biasK[r] == 0.f) ? 1.f : 0.f;
            len += v;
            s += v * xs[r * ND + tid];
        }
        xr[tid] = s / fmaxf(len, 1.f);
    }
    __syncthreads();

    // ---- cls1: 256 owners x 2 cols -> tmp[0..512) ----
    if (tid < 256) {
        const int c = tid;
        const f4* w0 = reinterpret_cast<const f4*>(c1w + (size_t)c * ND);
        const f4* w1 = reinterpret_cast<const f4*>(c1w + (size_t)(c + 256) * ND);
        const f4* ct4 = reinterpret_cast<const f4*>(xr);
        float a0 = 0.f, a1 = 0.f;
        for (int k4 = 0; k4 < 64; k4++) {
            f4 cv = ct4[k4];
            a0 += dot4(w0[k4], cv);
            a1 += dot4(w1[k4], cv);
        }
        tmp[c] = fmaxf(a0 + c1b[c], 0.f);
        tmp[c + 256] = fmaxf(a1 + c1b[c + 256], 0.f);
    }
    __syncthreads();

    // ---- cls2: 396 outputs ----
    if (tid < NCL) {
        const f4* w4 = reinterpret_cast<const f4*>(c2w + (size_t)tid * NF);
        const f4* h4 = reinterpret_cast<const f4*>(tmp);
        float acc = 0.f;
        for (int k4 = 0; k4 < 128; k4++) acc += dot4(w4[k4], h4[k4]);
        out[(size_t)b * NCL + tid] = acc + c2b[tid];
    }
}

// ---------------------------------------------------------------------------
extern "C" void kernel_launch(void* const* d_in, const int* in_sizes, int n_in,
                              void* d_out, int out_size, void* d_ws, size_t ws_size,
                              hipStream_t stream)
{
    const float* pred = (const float*)d_in[0];
    const float* hs   = (const float*)d_in[1];
    const float* f0   = (const float*)d_in[2];
    const float* f1   = (const float*)d_in[3];
    const float* f2   = (const float*)d_in[4];
    const float* f3   = (const float*)d_in[5];
    const float* ipw  = (const float*)d_in[6];
    const float* ipb  = (const float*)d_in[7];
    const float* inw  = (const float*)d_in[8];
    const float* inb  = (const float*)d_in[9];
    const float* ow   = (const float*)d_in[10];
    const float* ob   = (const float*)d_in[11];
    const float* l1w  = (const float*)d_in[12];
    const float* l1b  = (const float*)d_in[13];
    const float* l2w  = (const float*)d_in[14];
    const float* l2b  = (const float*)d_in[15];
    const float* ln1w = (const float*)d_in[16];
    const float* ln1b = (const float*)d_in[17];
    const float* ln2w = (const float*)d_in[18];
    const float* ln2b = (const float*)d_in[19];
    const float* c1w  = (const float*)d_in[20];
    const float* c1b  = (const float*)d_in[21];
    const float* c2w  = (const float*)d_in[22];
    const float* c2b  = (const float*)d_in[23];

    float* ws = (float*)d_ws;
    float* pooled = ws;                    // 65536
    float* tokG   = pooled + NB * 4 * ND;  // 98304
    float* biasW  = tokG + NB * 1536;      // 1024

    pool_cls_kernel<<<NB + 4 * NB * ND, 256, 0, stream>>>(
        pred, hs, f0, f1, f2, f3, pooled, tokG, biasW);
    xform_kernel<<<NB, 512, 0, stream>>>(
        pooled, tokG, biasW, ipw, ipb, inw, inb, ow, ob, l1w, l1b, l2w, l2b,
        ln1w, ln1b, ln2w, ln2b, c1w, c1b, c2w, c2b, (float*)d_out);
}